// Round 1
// baseline (161.940 us; speedup 1.0000x reference)
//
#include <hip/hip_runtime.h>
#include <hip/hip_bf16.h>
#include <math.h>

#define TPB 64  // one wave per block

// Kernel 1: per (batch, chunk-of-64-pred-points) block.
// Stages the batch's entire target set in LDS, each thread owns one pred
// point, computes min-squared-distance over all targets (sqrt hoisted out
// of the loop by monotonicity), plus the per-point correspondence (ADD) term.
// Writes per-block partial sums (fixed order -> deterministic).
__global__ __launch_bounds__(TPB) void chamfer_partial_kernel(
    const float* __restrict__ pred, const float* __restrict__ targ,
    float* __restrict__ partial, int N, int chunksPerBatch, int gridTotal) {
  extern __shared__ float st[];  // 3*N floats

  const int blk = blockIdx.x;
  const int b = blk / chunksPerBatch;
  const int c = blk % chunksPerBatch;

  const float* tb = targ + (size_t)b * N * 3;

  // Stage targets: N*3 floats, vectorized float4, coalesced.
  const int total4 = (N * 3) >> 2;
  const float4* tb4 = (const float4*)tb;
  float4* st4 = (float4*)st;
  for (int i = threadIdx.x; i < total4; i += TPB) st4[i] = tb4[i];
  __syncthreads();

  const int n = c * TPB + threadIdx.x;  // pred point owned by this thread
  const float* p = pred + ((size_t)b * N + n) * 3;
  const float px = p[0], py = p[1], pz = p[2];

  float dmin = 3.4e38f;
#pragma unroll 8
  for (int m = 0; m < N; ++m) {
    // All 64 lanes read the same LDS address -> broadcast, conflict-free.
    const float tx = st[m * 3 + 0];
    const float ty = st[m * 3 + 1];
    const float tz = st[m * 3 + 2];
    const float dx = px - tx;
    const float dy = py - ty;
    const float dz = pz - tz;
    const float d2 = dx * dx + dy * dy + dz * dz;
    dmin = fminf(dmin, d2);
  }
  // sqrt(max(min d2, EPS)) == min over sqrt(max(d2, EPS))  (monotone)
  const float sym = sqrtf(fmaxf(dmin, 1e-12f));

  // ADD (asym) term: distance to the corresponding target point.
  const float ax = px - st[n * 3 + 0];
  const float ay = py - st[n * 3 + 1];
  const float az = pz - st[n * 3 + 2];
  const float asym = sqrtf(ax * ax + ay * ay + az * az);

  // Wave-64 shuffle reduction (single wave per block).
  float s = sym, a = asym;
#pragma unroll
  for (int off = 32; off > 0; off >>= 1) {
    s += __shfl_down(s, off);
    a += __shfl_down(a, off);
  }
  if (threadIdx.x == 0) {
    partial[blk] = s;
    partial[gridTotal + blk] = a;
  }
}

// Kernel 2: deterministic finalize. Fixed-order serial sums (tiny work).
__global__ __launch_bounds__(64) void chamfer_finalize_kernel(
    const float* __restrict__ partial, const float* __restrict__ sym_flag,
    float* __restrict__ out, int B, int chunksPerBatch, int gridTotal,
    float invN) {
  __shared__ float s_loss[64];
  const int tid = threadIdx.x;
  if (tid < B) {
    float s = 0.f, a = 0.f;
    const int base = tid * chunksPerBatch;
    for (int c = 0; c < chunksPerBatch; ++c) {
      s += partial[base + c];
      a += partial[gridTotal + base + c];
    }
    const float f = sym_flag[tid];
    s_loss[tid] = f * (s * invN) + (1.f - f) * (a * invN);
  }
  __syncthreads();
  if (tid == 0) {
    float t = 0.f;
    for (int b = 0; b < B; ++b) t += s_loss[b];
    out[0] = t / (float)B;
  }
}

extern "C" void kernel_launch(void* const* d_in, const int* in_sizes, int n_in,
                              void* d_out, int out_size, void* d_ws, size_t ws_size,
                              hipStream_t stream) {
  const float* pred = (const float*)d_in[0];
  const float* targ = (const float*)d_in[1];
  const float* sym_flag = (const float*)d_in[2];
  float* out = (float*)d_out;

  const int B = in_sizes[2];               // 16
  const int N = in_sizes[0] / (B * 3);     // 2048

  const int chunksPerBatch = N / TPB;      // 32
  const int gridTotal = B * chunksPerBatch;  // 512

  float* partial = (float*)d_ws;           // gridTotal*2 floats

  const size_t ldsBytes = (size_t)N * 3 * sizeof(float);  // 24 KB
  chamfer_partial_kernel<<<gridTotal, TPB, ldsBytes, stream>>>(
      pred, targ, partial, N, chunksPerBatch, gridTotal);

  chamfer_finalize_kernel<<<1, 64, 0, stream>>>(
      partial, sym_flag, out, B, chunksPerBatch, gridTotal, 1.0f / (float)N);
}

// Round 2
// 22.701 us; speedup vs baseline: 7.1337x; 7.1337x over previous
//
#include <hip/hip_runtime.h>
#include <hip/hip_bf16.h>
#include <math.h>

#define K1_TPB 256
#define PPT 4  // pred points per thread

// Kernel 1: block = (batch b, pred-chunk pc, target-chunk tc).
// Stage the target chunk in LDS as float4 (tx,ty,tz, 0.5*t^2); each thread
// owns PPT pred points and keeps running min of s = 0.5*t^2 - p.t  (monotone
// in d^2 = 2*(s + 0.5*p^2), with 0.5*p^2 hoisted out of the whole loop).
// 1 broadcast ds_read_b128 + 4*PPT VALU per target.
__global__ __launch_bounds__(K1_TPB) void chamfer_min_kernel(
    const float* __restrict__ pred, const float* __restrict__ targ,
    float* __restrict__ pmin, int N, int B, int predChunks, int TC) {
  __shared__ float4 sh[256];

  const int blk = blockIdx.x;
  const int tc = blk % TC;
  const int rest = blk / TC;
  const int pc = rest % predChunks;
  const int b = rest / predChunks;

  const int tcSize = N / TC;  // targets per chunk (<=256)

  const float* tb = targ + ((size_t)b * N + (size_t)tc * tcSize) * 3;
  for (int i = threadIdx.x; i < tcSize; i += K1_TPB) {
    const float tx = tb[i * 3 + 0], ty = tb[i * 3 + 1], tz = tb[i * 3 + 2];
    sh[i] = make_float4(tx, ty, tz, 0.5f * (tx * tx + ty * ty + tz * tz));
  }
  __syncthreads();

  const int predBase = pc * (K1_TPB * PPT);
  const float* pb = pred + ((size_t)b * N + predBase) * 3;

  float npx[PPT], npy[PPT], npz[PPT], smin[PPT];
#pragma unroll
  for (int j = 0; j < PPT; ++j) {
    const int idx = j * K1_TPB + threadIdx.x;
    npx[j] = -pb[idx * 3 + 0];
    npy[j] = -pb[idx * 3 + 1];
    npz[j] = -pb[idx * 3 + 2];
    smin[j] = 3.4e38f;
  }

#pragma unroll 4
  for (int m = 0; m < tcSize; ++m) {
    const float4 t = sh[m];  // broadcast read, conflict-free
#pragma unroll
    for (int j = 0; j < PPT; ++j) {
      const float s = fmaf(npx[j], t.x, fmaf(npy[j], t.y, fmaf(npz[j], t.z, t.w)));
      smin[j] = fminf(smin[j], s);
    }
  }

  // pmin layout: [tc][b][pred]  (coalesced writes, stride-K1_TPB per j)
  float* dst = pmin + ((size_t)tc * B + b) * N + predBase;
#pragma unroll
  for (int j = 0; j < PPT; ++j) dst[j * K1_TPB + threadIdx.x] = smin[j];
}

#define K2_TPB 256

// Kernel 2: one pred point per thread. Min over target-chunks, recover the
// distance, plus the ADD (asym) per-point term. Fixed-order block reduction
// -> per-(batch, subblock) partial sums.
__global__ __launch_bounds__(K2_TPB) void chamfer_reduce_kernel(
    const float* __restrict__ pred, const float* __restrict__ targ,
    const float* __restrict__ pmin, float* __restrict__ psum,
    int N, int B, int TC, int blocksPerBatch, int nK2) {
  const int blk = blockIdx.x;
  const int b = blk / blocksPerBatch;
  const int sb = blk % blocksPerBatch;
  const int i = sb * K2_TPB + threadIdx.x;  // pred index within batch

  const size_t idx = (size_t)b * N + i;

  float smin = 3.4e38f;
  const size_t bnStride = (size_t)B * N;
  for (int tc = 0; tc < TC; ++tc)
    smin = fminf(smin, pmin[(size_t)tc * bnStride + idx]);

  const float* p = pred + idx * 3;
  const float* t = targ + idx * 3;
  const float px = p[0], py = p[1], pz = p[2];
  const float hp2 = 0.5f * (px * px + py * py + pz * pz);
  const float d2 = 2.0f * (smin + hp2);
  float sym = sqrtf(fmaxf(d2, 1e-12f));

  const float dx = px - t[0], dy = py - t[1], dz = pz - t[2];
  float asym = sqrtf(dx * dx + dy * dy + dz * dz);

  // wave shuffle reduce, then cross-wave via LDS (fixed order)
#pragma unroll
  for (int off = 32; off > 0; off >>= 1) {
    sym += __shfl_down(sym, off);
    asym += __shfl_down(asym, off);
  }
  __shared__ float ssym[K2_TPB / 64], sasym[K2_TPB / 64];
  const int wave = threadIdx.x >> 6;
  if ((threadIdx.x & 63) == 0) {
    ssym[wave] = sym;
    sasym[wave] = asym;
  }
  __syncthreads();
  if (threadIdx.x == 0) {
    float s = 0.f, a = 0.f;
#pragma unroll
    for (int w = 0; w < K2_TPB / 64; ++w) {
      s += ssym[w];
      a += sasym[w];
    }
    psum[blk] = s;
    psum[nK2 + blk] = a;
  }
}

// Kernel 3: tiny deterministic finalize.
__global__ __launch_bounds__(64) void chamfer_final_kernel(
    const float* __restrict__ psum, const float* __restrict__ sym_flag,
    float* __restrict__ out, int B, int blocksPerBatch, int nK2, float invN) {
  __shared__ float sl[64];
  const int tid = threadIdx.x;
  if (tid < B) {
    float s = 0.f, a = 0.f;
    const int base = tid * blocksPerBatch;
    for (int k = 0; k < blocksPerBatch; ++k) {
      s += psum[base + k];
      a += psum[nK2 + base + k];
    }
    const float f = sym_flag[tid];
    sl[tid] = f * (s * invN) + (1.f - f) * (a * invN);
  }
  __syncthreads();
  if (tid == 0) {
    float tot = 0.f;
    for (int b = 0; b < B; ++b) tot += sl[b];
    out[0] = tot / (float)B;
  }
}

extern "C" void kernel_launch(void* const* d_in, const int* in_sizes, int n_in,
                              void* d_out, int out_size, void* d_ws, size_t ws_size,
                              hipStream_t stream) {
  const float* pred = (const float*)d_in[0];
  const float* targ = (const float*)d_in[1];
  const float* sym_flag = (const float*)d_in[2];
  float* out = (float*)d_out;

  const int B = in_sizes[2];            // 16
  const int N = in_sizes[0] / (B * 3);  // 2048

  const int predChunks = N / (K1_TPB * PPT);      // 2
  const int blocksPerBatch = N / K2_TPB;          // 8
  const int nK2 = B * blocksPerBatch;             // 128

  // Pick TC (target chunks) to fit ws: pmin = TC*B*N floats + 2*nK2 floats.
  int TC = 32;
  while (TC > 1 &&
         ((size_t)TC * B * N + 2 * (size_t)nK2) * sizeof(float) > ws_size)
    TC >>= 1;

  float* pmin = (float*)d_ws;
  float* psum = pmin + (size_t)TC * B * N;

  const int gridK1 = B * predChunks * TC;  // 1024 at TC=32
  chamfer_min_kernel<<<gridK1, K1_TPB, 0, stream>>>(pred, targ, pmin, N, B,
                                                    predChunks, TC);
  chamfer_reduce_kernel<<<nK2, K2_TPB, 0, stream>>>(pred, targ, pmin, psum, N,
                                                    B, TC, blocksPerBatch, nK2);
  chamfer_final_kernel<<<1, 64, 0, stream>>>(psum, sym_flag, out, B,
                                             blocksPerBatch, nK2,
                                             1.0f / (float)N);
}